// Round 9
// baseline (646.309 us; speedup 1.0000x reference)
//
#include <hip/hip_runtime.h>
#include <hip/hip_bf16.h>
#include <math.h>

#define N_NODES 50000
#define N_EDGES 800000
#define EP (N_EDGES + N_NODES)   // edges + self loops
#define G_GRAPHS 512
#define HID 256
#define HEADS 8
#define NEG_SLOPE 0.2f
#define BN_EPS 1e-5f
#define NB_SCAN ((N_NODES + 1023) / 1024)   // 49

// prep kernel partition
#define NB_CVT 6250                          // 50000*128/4/256
#define NB_WT  256
#define NB_HIST ((EP + 255) / 256)           // 3321
#define NB_GST 3
#define NB_PREP (NB_CVT + NB_WT + NB_HIST + NB_GST)

typedef __attribute__((ext_vector_type(8))) short short8;
typedef __attribute__((ext_vector_type(8))) unsigned short ushort8v;
typedef __attribute__((ext_vector_type(4))) float floatx4;

__device__ __forceinline__ float bf2f(ushort u) {
    return __uint_as_float(((unsigned)u) << 16);
}
__device__ __forceinline__ ushort f2bf(float f) {
    unsigned u = __float_as_uint(f);
    u += 0x7fff + ((u >> 16) & 1);   // RNE
    return (ushort)(u >> 16);
}

// ---------------- fused prep: cvt(x->bf16) + Wt transpose + hist + gstart ----------------
__global__ __launch_bounds__(256) void prep_kernel(
    const float* __restrict__ x, ushort* __restrict__ xb,
    const float* __restrict__ W0, const float* __restrict__ W1,
    const float* __restrict__ W2, ushort* __restrict__ Wt0,
    ushort* __restrict__ Wt1, ushort* __restrict__ Wt2,
    const int* __restrict__ ei, int* __restrict__ fill,
    const int* __restrict__ batch, int* __restrict__ gstart) {
    int b = blockIdx.x;
    int tid = threadIdx.x;
    if (b < NB_CVT) {
        int i = b * 256 + tid;            // < 1,600,000 exactly
        float4 v = *(const float4*)&x[(size_t)i * 4];
        ushort4 o = {f2bf(v.x), f2bf(v.y), f2bf(v.z), f2bf(v.w)};
        *(ushort4*)&xb[(size_t)i * 4] = o;
    } else if (b < NB_CVT + NB_WT) {
        int c = b - NB_CVT;
        if (tid < 128) Wt0[c * 128 + tid] = f2bf(W0[(size_t)tid * HID + c]);
        Wt1[c * 256 + tid] = f2bf(W1[(size_t)tid * HID + c]);
        Wt2[c * 256 + tid] = f2bf(W2[(size_t)tid * HID + c]);
    } else if (b < NB_CVT + NB_WT + NB_HIST) {
        int e = (b - NB_CVT - NB_WT) * 256 + tid;
        if (e < EP) {
            int d = (e < N_EDGES) ? ei[N_EDGES + e] : (e - N_EDGES);
            atomicAdd(&fill[d], 1);
        }
    } else {
        int g = (b - NB_CVT - NB_WT - NB_HIST) * 256 + tid;
        if (g <= G_GRAPHS) {
            int lo = 0, hi = N_NODES;
            while (lo < hi) { int mid = (lo + hi) >> 1; if (batch[mid] < g) lo = mid + 1; else hi = mid; }
            gstart[g] = lo;
        }
    }
}

// ---------------- CSR scan ----------------
__global__ void scan1_kernel(const int* __restrict__ fill, int* __restrict__ rowptr,
                             int* __restrict__ bsum) {
    __shared__ int sdata[1024];
    int tid = threadIdx.x;
    int idx = blockIdx.x * 1024 + tid;
    int v = (idx < N_NODES) ? fill[idx] : 0;
    sdata[tid] = v;
    __syncthreads();
    for (int off = 1; off < 1024; off <<= 1) {
        int x = (tid >= off) ? sdata[tid - off] : 0;
        __syncthreads();
        sdata[tid] += x;
        __syncthreads();
    }
    if (idx < N_NODES) rowptr[idx] = sdata[tid] - v;
    if (tid == 1023) bsum[blockIdx.x] = sdata[1023];
}

__global__ void scan3_kernel(int* __restrict__ rowptr, int* __restrict__ fill,
                             const int* __restrict__ bsum) {
    __shared__ int soff[2];
    int tid = threadIdx.x;
    if (tid < 64) {
        int v = (tid < NB_SCAN) ? bsum[tid] : 0;
        int incl = v;
#pragma unroll
        for (int off = 1; off < 64; off <<= 1) {
            int x = __shfl_up(incl, off, 64);
            if (tid >= off) incl += x;
        }
        if (tid == blockIdx.x) soff[0] = incl - v;
        if (tid == NB_SCAN - 1) soff[1] = incl;
    }
    __syncthreads();
    int idx = blockIdx.x * 1024 + tid;
    if (idx < N_NODES) {
        int e = rowptr[idx] + soff[0];
        rowptr[idx] = e;
        fill[idx] = e;
    }
    if (idx == N_NODES) rowptr[N_NODES] = soff[1];
}

__global__ void scatter_kernel(const int* __restrict__ ei, int* __restrict__ fill,
                               int* __restrict__ esrc) {
    int e = blockIdx.x * 256 + threadIdx.x;
    if (e >= EP) return;
    int s, d;
    if (e < N_EDGES) { s = ei[e]; d = ei[N_EDGES + e]; }
    else             { s = d = e - N_EDGES; }
    int pos = atomicAdd(&fill[d], 1);
    esrc[pos] = s;
}

// ---------------- MFMA GEMM + fused attention scores ----------------
// C[M,256] = A[M,K] @ Wt[256,K]^T (bf16 in/out), 128x128 tile, BK=64, dbuf, counted vmcnt.
// Epilogue: per-row per-head partial scores (fp32 acc · a_src/a_dst) atomicAdd'ed into
// ssrc/sdst (pre-zeroed; 2 contributing blocks per row).
#define BM 128
#define BN 128
#define BK 64

__global__ __launch_bounds__(256) void gemm_kernel(
    const ushort* __restrict__ A, const ushort* __restrict__ Bt,
    ushort* __restrict__ C, int M, int K,
    const float* __restrict__ asf, const float* __restrict__ adf,
    float* __restrict__ ssrc, float* __restrict__ sdst)
{
    __shared__ __align__(16) char As[2][BM * BK * 2];   // 2 x 16KB
    __shared__ __align__(16) char Bs[2][BN * BK * 2];

    int t = threadIdx.x;
    int w = t >> 6, lane = t & 63;
    int bm = blockIdx.x * BM, bn = blockIdx.y * BN;
    int wr = (w >> 1) * 64, wc = (w & 1) * 64;

    floatx4 acc[4][4] = {};

    int l8 = lane >> 3;
    int cb = ((lane & 7) << 4) ^ ((l8 & 7) << 4);  // pre-swizzled source byte
    int rsw = (lane & 7) << 4;                     // read-side swizzle
    int nt = K / BK;

    auto stage = [&](int buf, int k0) {
#pragma unroll
        for (int c = 0; c < 4; c++) {
            int q = w * 4 + c;
            int row = q * 8 + l8;
            int ar = bm + row; if (ar > M - 1) ar = M - 1;
            const char* src = (const char*)A + ((size_t)ar * K + k0) * 2 + cb;
            __builtin_amdgcn_global_load_lds(
                (const __attribute__((address_space(1))) void*)src,
                (__attribute__((address_space(3))) void*)&As[buf][q * 1024], 16, 0, 0);
            int br = bn + row;
            const char* srcb = (const char*)Bt + ((size_t)br * K + k0) * 2 + cb;
            __builtin_amdgcn_global_load_lds(
                (const __attribute__((address_space(1))) void*)srcb,
                (__attribute__((address_space(3))) void*)&Bs[buf][q * 1024], 16, 0, 0);
        }
    };

    stage(0, 0);                                    // 8 loads in flight
    for (int tt = 0; tt < nt; tt++) {
        int cur = tt & 1;
        __builtin_amdgcn_s_barrier();
        if (tt + 1 < nt) {
            stage(cur ^ 1, (tt + 1) * BK);          // 8 more in flight
            asm volatile("s_waitcnt vmcnt(8)" ::: "memory");
        } else {
            asm volatile("s_waitcnt vmcnt(0)" ::: "memory");
        }
        __builtin_amdgcn_sched_barrier(0);
        __builtin_amdgcn_s_barrier();
        __builtin_amdgcn_sched_barrier(0);

        const char* asb = As[cur];
        const char* bsb = Bs[cur];
#pragma unroll
        for (int ks = 0; ks < 2; ks++) {
            int kb = ks * 64 + ((lane >> 4) << 4);
            short8 a[4], b[4];
#pragma unroll
            for (int m = 0; m < 4; m++) {
                int row = wr + m * 16 + (lane & 15);
                a[m] = *(const short8*)&asb[row * 128 + (kb ^ rsw)];
            }
#pragma unroll
            for (int n = 0; n < 4; n++) {
                int row = wc + n * 16 + (lane & 15);
                b[n] = *(const short8*)&bsb[row * 128 + (kb ^ rsw)];
            }
#pragma unroll
            for (int m = 0; m < 4; m++)
#pragma unroll
                for (int n = 0; n < 4; n++)
                    acc[m][n] = __builtin_amdgcn_mfma_f32_16x16x32_bf16(a[m], b[n], acc[m][n], 0, 0, 0);
        }
    }

    int cl = lane & 15, rh = lane >> 4;
#pragma unroll
    for (int m = 0; m < 4; m++) {
#pragma unroll
        for (int r = 0; r < 4; r++) {
            int row = bm + wr + m * 16 + rh * 4 + r;
            if (row < M) {
                size_t base = (size_t)row * HID + bn + wc;
#pragma unroll
                for (int n = 0; n < 4; n++)
                    C[base + n * 16 + cl] = f2bf(acc[m][n][r]);
            }
        }
    }

    // ---- fused score epilogue ----
    // this wave's cols: base_c + n*16 + cl; n in {0,1} -> head base_c>>5, n in {2,3} -> +1
    int base_c = bn + wc;
    float av[4], dv[4];
#pragma unroll
    for (int n = 0; n < 4; n++) {
        av[n] = asf[base_c + n * 16 + cl];
        dv[n] = adf[base_c + n * 16 + cl];
    }
    int headA = base_c >> 5, headB = headA + 1;
#pragma unroll
    for (int m = 0; m < 4; m++) {
#pragma unroll
        for (int r = 0; r < 4; r++) {
            int row = bm + wr + m * 16 + rh * 4 + r;
            float psA = acc[m][0][r] * av[0] + acc[m][1][r] * av[1];
            float psB = acc[m][2][r] * av[2] + acc[m][3][r] * av[3];
            float pdA = acc[m][0][r] * dv[0] + acc[m][1][r] * dv[1];
            float pdB = acc[m][2][r] * dv[2] + acc[m][3][r] * dv[3];
#pragma unroll
            for (int off = 1; off < 16; off <<= 1) {
                psA += __shfl_xor(psA, off, 64);
                psB += __shfl_xor(psB, off, 64);
                pdA += __shfl_xor(pdA, off, 64);
                pdB += __shfl_xor(pdB, off, 64);
            }
            if (cl == 0 && row < M) {
                atomicAdd(&ssrc[(unsigned)row * 8u + headA], psA);
                atomicAdd(&ssrc[(unsigned)row * 8u + headB], psB);
                atomicAdd(&sdst[(unsigned)row * 8u + headA], pdA);
                atomicAdd(&sdst[(unsigned)row * 8u + headB], pdB);
            }
        }
    }
}

// ---------------- aggregation: one wave per node, 2 edge slots x 32 channel-lanes ----------
__global__ __launch_bounds__(256) void agg_kernel(
    const ushort* __restrict__ hb, const float* __restrict__ ssrc,
    const float* __restrict__ sdst, const int* __restrict__ rowptr,
    const int* __restrict__ esrc, const float* __restrict__ bias,
    const float* __restrict__ gam, const float* __restrict__ bet,
    const float* __restrict__ bmean, const float* __restrict__ bvar,
    const ushort* __restrict__ residb, ushort* __restrict__ outb) {
    int wid = threadIdx.x >> 6;
    int lane = threadIdx.x & 63;
    int n = blockIdx.x * 4 + wid;
    if (n >= N_NODES) return;
    int start = rowptr[n], end = rowptr[n + 1];
    int slot = lane >> 5;
    unsigned cl = lane & 31;
    unsigned c0 = cl * 8u;
    unsigned head = cl >> 2;
    float sdh = sdst[(unsigned)n * 8u + head];

    float z = 0.f;
    float acc[8] = {};
    int i = start + slot;
    for (; i + 6 < end; i += 8) {
        unsigned s0 = (unsigned)esrc[i], s1 = (unsigned)esrc[i + 2];
        unsigned s2 = (unsigned)esrc[i + 4], s3 = (unsigned)esrc[i + 6];
        float a0 = ssrc[s0 * 8u + head] + sdh;
        float a1 = ssrc[s1 * 8u + head] + sdh;
        float a2 = ssrc[s2 * 8u + head] + sdh;
        float a3 = ssrc[s3 * 8u + head] + sdh;
        ushort8v h0 = *(const ushort8v*)&hb[s0 * 256u + c0];
        ushort8v h1 = *(const ushort8v*)&hb[s1 * 256u + c0];
        ushort8v h2 = *(const ushort8v*)&hb[s2 * 256u + c0];
        ushort8v h3 = *(const ushort8v*)&hb[s3 * 256u + c0];
        a0 = fmaxf(a0, NEG_SLOPE * a0);
        a1 = fmaxf(a1, NEG_SLOPE * a1);
        a2 = fmaxf(a2, NEG_SLOPE * a2);
        a3 = fmaxf(a3, NEG_SLOPE * a3);
        float e0 = __expf(a0), e1 = __expf(a1), e2 = __expf(a2), e3 = __expf(a3);
        z += (e0 + e1) + (e2 + e3);
#pragma unroll
        for (int j = 0; j < 8; j++)
            acc[j] += (e0 * bf2f(h0[j]) + e1 * bf2f(h1[j])) +
                      (e2 * bf2f(h2[j]) + e3 * bf2f(h3[j]));
    }
    for (; i < end; i += 2) {
        unsigned s = (unsigned)esrc[i];
        float a = ssrc[s * 8u + head] + sdh;
        a = fmaxf(a, NEG_SLOPE * a);
        float e = __expf(a);
        ushort8v hv = *(const ushort8v*)&hb[s * 256u + c0];
        z += e;
#pragma unroll
        for (int j = 0; j < 8; j++)
            acc[j] += e * bf2f(hv[j]);
    }
    z += __shfl_xor(z, 32, 64);
#pragma unroll
    for (int j = 0; j < 8; j++)
        acc[j] += __shfl_xor(acc[j], 32, 64);

    if (lane < 32) {
        float inv = 1.f / (z + 1e-16f);
        float4 bv0 = *(const float4*)&bias[c0],   bv1 = *(const float4*)&bias[c0 + 4];
        float4 gv0 = *(const float4*)&gam[c0],    gv1 = *(const float4*)&gam[c0 + 4];
        float4 be0 = *(const float4*)&bet[c0],    be1 = *(const float4*)&bet[c0 + 4];
        float4 mv0 = *(const float4*)&bmean[c0],  mv1 = *(const float4*)&bmean[c0 + 4];
        float4 vv0 = *(const float4*)&bvar[c0],   vv1 = *(const float4*)&bvar[c0 + 4];
        float bs[8] = {bv0.x, bv0.y, bv0.z, bv0.w, bv1.x, bv1.y, bv1.z, bv1.w};
        float gs[8] = {gv0.x, gv0.y, gv0.z, gv0.w, gv1.x, gv1.y, gv1.z, gv1.w};
        float bes[8] = {be0.x, be0.y, be0.z, be0.w, be1.x, be1.y, be1.z, be1.w};
        float ms[8] = {mv0.x, mv0.y, mv0.z, mv0.w, mv1.x, mv1.y, mv1.z, mv1.w};
        float vs[8] = {vv0.x, vv0.y, vv0.z, vv0.w, vv1.x, vv1.y, vv1.z, vv1.w};
        float rs[8] = {};
        if (residb) {
            ushort8v rv = *(const ushort8v*)&residb[(unsigned)n * 256u + c0];
#pragma unroll
            for (int j = 0; j < 8; j++) rs[j] = bf2f(rv[j]);
        }
        ushort8v ob;
#pragma unroll
        for (int j = 0; j < 8; j++) {
            float val = acc[j] * inv + bs[j];
            val = (val - ms[j]) * rsqrtf(vs[j] + BN_EPS) * gs[j] + bes[j];
            val += rs[j];
            val = (val > 0.f) ? val : expm1f(val);   // ELU
            ob[j] = f2bf(val);
        }
        *(ushort8v*)&outb[(unsigned)n * 256u + c0] = ob;
    }
}

// ---------------- fused pooling + output heads ----------------
__global__ void poolhead_kernel(const ushort* __restrict__ hbf, const int* __restrict__ gstart,
                                const float* __restrict__ ow0, const float* __restrict__ ob0,
                                const float* __restrict__ ow1, const float* __restrict__ ob1,
                                float* __restrict__ out) {
    int g = blockIdx.x;
    int t = threadIdx.x;
    int s = gstart[g], e = gstart[g + 1];
    float sum = 0.f, mx = -INFINITY;
    for (int n = s; n < e; n++) {
        float v = bf2f(hbf[(unsigned)n * 256u + t]);
        sum += v;
        mx = fmaxf(mx, v);
    }
    int cnt = e - s;
    float mean = sum / fmaxf((float)cnt, 1.f);
    if (cnt == 0) mx = 0.f;

    float a0[3], a1[3];
#pragma unroll
    for (int j = 0; j < 3; j++) {
        a0[j] = mean * ow0[t * 3 + j] + sum * ow0[(256 + t) * 3 + j] + mx * ow0[(512 + t) * 3 + j];
        a1[j] = mean * ow1[t * 3 + j] + sum * ow1[(256 + t) * 3 + j] + mx * ow1[(512 + t) * 3 + j];
    }
    __shared__ float sd[6][256];
#pragma unroll
    for (int j = 0; j < 3; j++) { sd[j][t] = a0[j]; sd[3 + j][t] = a1[j]; }
    __syncthreads();
    for (int off = 128; off; off >>= 1) {
        if (t < off) {
#pragma unroll
            for (int j = 0; j < 6; j++) sd[j][t] += sd[j][t + off];
        }
        __syncthreads();
    }
    if (t < 3) {
        out[g * 3 + t] = sd[t][0] + ob0[t];
        out[1536 + g * 3 + t] = sd[3 + t][0] + ob1[t];
    }
}

// ---------------- launch ----------------
extern "C" void kernel_launch(void* const* d_in, const int* in_sizes, int n_in,
                              void* d_out, int out_size, void* d_ws, size_t ws_size,
                              hipStream_t stream) {
    const float* x     = (const float*)d_in[0];
    const int*   ei    = (const int*)d_in[1];
    const int*   batch = (const int*)d_in[2];
    const float* W[3]  = {(const float*)d_in[3], (const float*)d_in[11], (const float*)d_in[19]};
    const float* AS[3] = {(const float*)d_in[4], (const float*)d_in[12], (const float*)d_in[20]};
    const float* AD[3] = {(const float*)d_in[5], (const float*)d_in[13], (const float*)d_in[21]};
    const float* B[3]  = {(const float*)d_in[6], (const float*)d_in[14], (const float*)d_in[22]};
    const float* GM[3] = {(const float*)d_in[7], (const float*)d_in[15], (const float*)d_in[23]};
    const float* BE[3] = {(const float*)d_in[8], (const float*)d_in[16], (const float*)d_in[24]};
    const float* M[3]  = {(const float*)d_in[9], (const float*)d_in[17], (const float*)d_in[25]};
    const float* V[3]  = {(const float*)d_in[10], (const float*)d_in[18], (const float*)d_in[26]};
    const float* ow0 = (const float*)d_in[27];
    const float* ob0 = (const float*)d_in[28];
    const float* ow1 = (const float*)d_in[29];
    const float* ob1 = (const float*)d_in[30];
    float* out = (float*)d_out;

    // workspace carve: [fill | scores x3] contiguous -> ONE memset zeroes all
    char* p = (char*)d_ws;
    int* fill   = (int*)p;  p += (size_t)N_NODES * 4;
    float* sc[3][2];
    for (int l = 0; l < 3; l++) {
        sc[l][0] = (float*)p; p += (size_t)N_NODES * HEADS * 4;   // ssrc
        sc[l][1] = (float*)p; p += (size_t)N_NODES * HEADS * 4;   // sdst
    }
    size_t zero_bytes = (size_t)p - (size_t)d_ws;
    int* rowptr = (int*)p;  p += (size_t)(N_NODES + 1) * 4;
    int* esrc   = (int*)p;  p += (size_t)EP * 4;
    int* gstart = (int*)p;  p += (size_t)(G_GRAPHS + 1) * 4;
    int* bsum   = (int*)p;  p += (size_t)(NB_SCAN + 1) * 4;
    p = (char*)(((uintptr_t)p + 255) & ~(uintptr_t)255);
    ushort* hb    = (ushort*)p; p += (size_t)N_NODES * HID * 2;      // GEMM out (bf16)
    ushort* curhb = (ushort*)p; p += (size_t)N_NODES * HID * 2;      // layer out (bf16)
    ushort* xb    = (ushort*)p; p += (size_t)N_NODES * 128 * 2;      // x bf16
    ushort* Wt0   = (ushort*)p; p += (size_t)256 * 128 * 2;
    ushort* Wt1   = (ushort*)p; p += (size_t)256 * 256 * 2;
    ushort* Wt2   = (ushort*)p; p += (size_t)256 * 256 * 2;

    hipMemsetAsync(d_ws, 0, zero_bytes, stream);    // fill + all scores

    prep_kernel<<<NB_PREP, 256, 0, stream>>>(x, xb, W[0], W[1], W[2], Wt0, Wt1, Wt2,
                                             ei, fill, batch, gstart);
    scan1_kernel<<<NB_SCAN, 1024, 0, stream>>>(fill, rowptr, bsum);
    scan3_kernel<<<NB_SCAN, 1024, 0, stream>>>(rowptr, fill, bsum);
    scatter_kernel<<<(EP + 255) / 256, 256, 0, stream>>>(ei, fill, esrc);

    const ushort* Wt[3] = {Wt0, Wt1, Wt2};
    dim3 ggrid((N_NODES + BM - 1) / BM, HID / BN);
    int agrid = (N_NODES + 3) / 4;

    // layer 1 (input xb, K=128, no residual)
    gemm_kernel<<<ggrid, 256, 0, stream>>>(xb, Wt[0], hb, N_NODES, 128,
                                           AS[0], AD[0], sc[0][0], sc[0][1]);
    agg_kernel<<<agrid, 256, 0, stream>>>(hb, sc[0][0], sc[0][1], rowptr, esrc,
                                          B[0], GM[0], BE[0], M[0], V[0],
                                          nullptr, curhb);
    // layers 2,3: residual read + output write both bf16, in place on curhb
    for (int l = 1; l < 3; l++) {
        gemm_kernel<<<ggrid, 256, 0, stream>>>(curhb, Wt[l], hb, N_NODES, 256,
                                               AS[l], AD[l], sc[l][0], sc[l][1]);
        agg_kernel<<<agrid, 256, 0, stream>>>(hb, sc[l][0], sc[l][1], rowptr, esrc,
                                              B[l], GM[l], BE[l], M[l], V[l],
                                              curhb, curhb);
    }

    // fused pooling + heads
    poolhead_kernel<<<G_GRAPHS, 256, 0, stream>>>(curhb, gstart, ow0, ob0, ow1, ob1, out);
}

// Round 10
// 546.690 us; speedup vs baseline: 1.1822x; 1.1822x over previous
//
#include <hip/hip_runtime.h>
#include <hip/hip_bf16.h>
#include <math.h>

#define N_NODES 50000
#define N_EDGES 800000
#define EP (N_EDGES + N_NODES)   // edges + self loops
#define G_GRAPHS 512
#define HID 256
#define HEADS 8
#define NEG_SLOPE 0.2f
#define BN_EPS 1e-5f
#define NB_SCAN ((N_NODES + 1023) / 1024)   // 49

// prep kernel partition
#define NB_CVT 6250                          // 50000*128/4/256
#define NB_WT  256
#define NB_HIST ((EP + 255) / 256)           // 3321
#define NB_GST 3
#define NB_PREP (NB_CVT + NB_WT + NB_HIST + NB_GST)

typedef __attribute__((ext_vector_type(8))) short short8;
typedef __attribute__((ext_vector_type(8))) unsigned short ushort8v;
typedef __attribute__((ext_vector_type(4))) float floatx4;

__device__ __forceinline__ float bf2f(ushort u) {
    return __uint_as_float(((unsigned)u) << 16);
}
__device__ __forceinline__ ushort f2bf(float f) {
    unsigned u = __float_as_uint(f);
    u += 0x7fff + ((u >> 16) & 1);   // RNE
    return (ushort)(u >> 16);
}

// ---------------- fused prep: cvt(x->bf16) + Wt transpose + hist + gstart ----------------
__global__ __launch_bounds__(256) void prep_kernel(
    const float* __restrict__ x, ushort* __restrict__ xb,
    const float* __restrict__ W0, const float* __restrict__ W1,
    const float* __restrict__ W2, ushort* __restrict__ Wt0,
    ushort* __restrict__ Wt1, ushort* __restrict__ Wt2,
    const int* __restrict__ ei, int* __restrict__ fill,
    const int* __restrict__ batch, int* __restrict__ gstart) {
    int b = blockIdx.x;
    int tid = threadIdx.x;
    if (b < NB_CVT) {
        int i = b * 256 + tid;            // < 1,600,000 exactly
        float4 v = *(const float4*)&x[(size_t)i * 4];
        ushort4 o = {f2bf(v.x), f2bf(v.y), f2bf(v.z), f2bf(v.w)};
        *(ushort4*)&xb[(size_t)i * 4] = o;
    } else if (b < NB_CVT + NB_WT) {
        int c = b - NB_CVT;
        if (tid < 128) Wt0[c * 128 + tid] = f2bf(W0[(size_t)tid * HID + c]);
        Wt1[c * 256 + tid] = f2bf(W1[(size_t)tid * HID + c]);
        Wt2[c * 256 + tid] = f2bf(W2[(size_t)tid * HID + c]);
    } else if (b < NB_CVT + NB_WT + NB_HIST) {
        int e = (b - NB_CVT - NB_WT) * 256 + tid;
        if (e < EP) {
            int d = (e < N_EDGES) ? ei[N_EDGES + e] : (e - N_EDGES);
            atomicAdd(&fill[d], 1);
        }
    } else {
        int g = (b - NB_CVT - NB_WT - NB_HIST) * 256 + tid;
        if (g <= G_GRAPHS) {
            int lo = 0, hi = N_NODES;
            while (lo < hi) { int mid = (lo + hi) >> 1; if (batch[mid] < g) lo = mid + 1; else hi = mid; }
            gstart[g] = lo;
        }
    }
}

// ---------------- CSR scan ----------------
__global__ void scan1_kernel(const int* __restrict__ fill, int* __restrict__ rowptr,
                             int* __restrict__ bsum) {
    __shared__ int sdata[1024];
    int tid = threadIdx.x;
    int idx = blockIdx.x * 1024 + tid;
    int v = (idx < N_NODES) ? fill[idx] : 0;
    sdata[tid] = v;
    __syncthreads();
    for (int off = 1; off < 1024; off <<= 1) {
        int x = (tid >= off) ? sdata[tid - off] : 0;
        __syncthreads();
        sdata[tid] += x;
        __syncthreads();
    }
    if (idx < N_NODES) rowptr[idx] = sdata[tid] - v;
    if (tid == 1023) bsum[blockIdx.x] = sdata[1023];
}

__global__ void scan3_kernel(int* __restrict__ rowptr, int* __restrict__ fill,
                             const int* __restrict__ bsum) {
    __shared__ int soff[2];
    int tid = threadIdx.x;
    if (tid < 64) {
        int v = (tid < NB_SCAN) ? bsum[tid] : 0;
        int incl = v;
#pragma unroll
        for (int off = 1; off < 64; off <<= 1) {
            int x = __shfl_up(incl, off, 64);
            if (tid >= off) incl += x;
        }
        if (tid == blockIdx.x) soff[0] = incl - v;
        if (tid == NB_SCAN - 1) soff[1] = incl;
    }
    __syncthreads();
    int idx = blockIdx.x * 1024 + tid;
    if (idx < N_NODES) {
        int e = rowptr[idx] + soff[0];
        rowptr[idx] = e;
        fill[idx] = e;
    }
    if (idx == N_NODES) rowptr[N_NODES] = soff[1];
}

__global__ void scatter_kernel(const int* __restrict__ ei, int* __restrict__ fill,
                               int* __restrict__ esrc) {
    int e = blockIdx.x * 256 + threadIdx.x;
    if (e >= EP) return;
    int s, d;
    if (e < N_EDGES) { s = ei[e]; d = ei[N_EDGES + e]; }
    else             { s = d = e - N_EDGES; }
    int pos = atomicAdd(&fill[d], 1);
    esrc[pos] = s;
}

// ---------------- MFMA GEMM: C[M,256] = A[M,K] @ Wt[256,K]^T (bf16 in/out) ----------------
// 128x128 tile, BK=64, double-buffered LDS, counted vmcnt (loads fly across barriers)
#define BM 128
#define BN 128
#define BK 64

__global__ __launch_bounds__(256) void gemm_kernel(
    const ushort* __restrict__ A, const ushort* __restrict__ Bt,
    ushort* __restrict__ C, int M, int K)
{
    __shared__ __align__(16) char As[2][BM * BK * 2];   // 2 x 16KB
    __shared__ __align__(16) char Bs[2][BN * BK * 2];

    int t = threadIdx.x;
    int w = t >> 6, lane = t & 63;
    int bm = blockIdx.x * BM, bn = blockIdx.y * BN;
    int wr = (w >> 1) * 64, wc = (w & 1) * 64;

    floatx4 acc[4][4] = {};

    int l8 = lane >> 3;
    int cb = ((lane & 7) << 4) ^ ((l8 & 7) << 4);  // pre-swizzled source byte
    int rsw = (lane & 7) << 4;                     // read-side swizzle
    int nt = K / BK;

    auto stage = [&](int buf, int k0) {
#pragma unroll
        for (int c = 0; c < 4; c++) {
            int q = w * 4 + c;
            int row = q * 8 + l8;
            int ar = bm + row; if (ar > M - 1) ar = M - 1;
            const char* src = (const char*)A + ((size_t)ar * K + k0) * 2 + cb;
            __builtin_amdgcn_global_load_lds(
                (const __attribute__((address_space(1))) void*)src,
                (__attribute__((address_space(3))) void*)&As[buf][q * 1024], 16, 0, 0);
            int br = bn + row;
            const char* srcb = (const char*)Bt + ((size_t)br * K + k0) * 2 + cb;
            __builtin_amdgcn_global_load_lds(
                (const __attribute__((address_space(1))) void*)srcb,
                (__attribute__((address_space(3))) void*)&Bs[buf][q * 1024], 16, 0, 0);
        }
    };

    stage(0, 0);                                    // 8 loads in flight
    for (int tt = 0; tt < nt; tt++) {
        int cur = tt & 1;
        // protect buf cur^1 (read by compute of iter tt-1) before restaging it
        __builtin_amdgcn_s_barrier();
        if (tt + 1 < nt) {
            stage(cur ^ 1, (tt + 1) * BK);          // 8 more in flight
            asm volatile("s_waitcnt vmcnt(8)" ::: "memory");   // wait own cur-tile loads
        } else {
            asm volatile("s_waitcnt vmcnt(0)" ::: "memory");
        }
        __builtin_amdgcn_sched_barrier(0);
        __builtin_amdgcn_s_barrier();               // all waves' cur-tile loads visible
        __builtin_amdgcn_sched_barrier(0);

        const char* asb = As[cur];
        const char* bsb = Bs[cur];
#pragma unroll
        for (int ks = 0; ks < 2; ks++) {
            int kb = ks * 64 + ((lane >> 4) << 4);
            short8 a[4], b[4];
#pragma unroll
            for (int m = 0; m < 4; m++) {
                int row = wr + m * 16 + (lane & 15);
                a[m] = *(const short8*)&asb[row * 128 + (kb ^ rsw)];
            }
#pragma unroll
            for (int n = 0; n < 4; n++) {
                int row = wc + n * 16 + (lane & 15);
                b[n] = *(const short8*)&bsb[row * 128 + (kb ^ rsw)];
            }
#pragma unroll
            for (int m = 0; m < 4; m++)
#pragma unroll
                for (int n = 0; n < 4; n++)
                    acc[m][n] = __builtin_amdgcn_mfma_f32_16x16x32_bf16(a[m], b[n], acc[m][n], 0, 0, 0);
        }
    }

    int cl = lane & 15, rh = lane >> 4;
#pragma unroll
    for (int m = 0; m < 4; m++) {
#pragma unroll
        for (int r = 0; r < 4; r++) {
            int row = bm + wr + m * 16 + rh * 4 + r;
            if (row < M) {
                size_t base = (size_t)row * HID + bn + wc;
#pragma unroll
                for (int n = 0; n < 4; n++)
                    C[base + n * 16 + cl] = f2bf(acc[m][n][r]);
            }
        }
    }
}

// ---------------- attention scores: wave = 2 nodes, lane = 16B chunk ----------------
__global__ __launch_bounds__(256) void score_kernel(
    const ushort* __restrict__ hb, const float* __restrict__ asrc,
    const float* __restrict__ adst, float* __restrict__ ssrc,
    float* __restrict__ sdst) {
    int t = threadIdx.x;
    int lane = t & 63;
    int wid = t >> 6;
    unsigned n = (unsigned)(blockIdx.x * 8 + wid * 2 + (lane >> 5));
    unsigned cl = lane & 31;
    unsigned c0 = cl * 8u;
    ushort8v hv = *(const ushort8v*)&hb[n * 256u + c0];
    float s1 = 0.f, s2 = 0.f;
#pragma unroll
    for (int j = 0; j < 8; j++) {
        float v = bf2f(hv[j]);
        s1 += v * asrc[c0 + j];
        s2 += v * adst[c0 + j];
    }
    s1 += __shfl_xor(s1, 1, 64); s2 += __shfl_xor(s2, 1, 64);
    s1 += __shfl_xor(s1, 2, 64); s2 += __shfl_xor(s2, 2, 64);
    if ((cl & 3) == 0) {
        unsigned h = cl >> 2;
        ssrc[n * 8u + h] = s1;
        sdst[n * 8u + h] = s2;
    }
}

// ---------------- aggregation: one wave per node, 2 edge slots x 32 channel-lanes ----------
// no max-subtraction: |alpha| <~ 10 here, exp(alpha) safe in fp32, e/sum(e) identical.
__global__ __launch_bounds__(256) void agg_kernel(
    const ushort* __restrict__ hb, const float* __restrict__ ssrc,
    const float* __restrict__ sdst, const int* __restrict__ rowptr,
    const int* __restrict__ esrc, const float* __restrict__ bias,
    const float* __restrict__ gam, const float* __restrict__ bet,
    const float* __restrict__ bmean, const float* __restrict__ bvar,
    const ushort* __restrict__ residb, ushort* __restrict__ outb) {
    int wid = threadIdx.x >> 6;
    int lane = threadIdx.x & 63;
    int n = blockIdx.x * 4 + wid;
    if (n >= N_NODES) return;
    int start = rowptr[n], end = rowptr[n + 1];
    int slot = lane >> 5;
    unsigned cl = lane & 31;
    unsigned c0 = cl * 8u;
    unsigned head = cl >> 2;
    float sdh = sdst[(unsigned)n * 8u + head];

    float z = 0.f;
    float acc[8] = {};
    int i = start + slot;
    for (; i + 6 < end; i += 8) {
        unsigned s0 = (unsigned)esrc[i], s1 = (unsigned)esrc[i + 2];
        unsigned s2 = (unsigned)esrc[i + 4], s3 = (unsigned)esrc[i + 6];
        float a0 = ssrc[s0 * 8u + head] + sdh;
        float a1 = ssrc[s1 * 8u + head] + sdh;
        float a2 = ssrc[s2 * 8u + head] + sdh;
        float a3 = ssrc[s3 * 8u + head] + sdh;
        ushort8v h0 = *(const ushort8v*)&hb[s0 * 256u + c0];
        ushort8v h1 = *(const ushort8v*)&hb[s1 * 256u + c0];
        ushort8v h2 = *(const ushort8v*)&hb[s2 * 256u + c0];
        ushort8v h3 = *(const ushort8v*)&hb[s3 * 256u + c0];
        a0 = fmaxf(a0, NEG_SLOPE * a0);
        a1 = fmaxf(a1, NEG_SLOPE * a1);
        a2 = fmaxf(a2, NEG_SLOPE * a2);
        a3 = fmaxf(a3, NEG_SLOPE * a3);
        float e0 = __expf(a0), e1 = __expf(a1), e2 = __expf(a2), e3 = __expf(a3);
        z += (e0 + e1) + (e2 + e3);
#pragma unroll
        for (int j = 0; j < 8; j++)
            acc[j] += (e0 * bf2f(h0[j]) + e1 * bf2f(h1[j])) +
                      (e2 * bf2f(h2[j]) + e3 * bf2f(h3[j]));
    }
    for (; i < end; i += 2) {
        unsigned s = (unsigned)esrc[i];
        float a = ssrc[s * 8u + head] + sdh;
        a = fmaxf(a, NEG_SLOPE * a);
        float e = __expf(a);
        ushort8v hv = *(const ushort8v*)&hb[s * 256u + c0];
        z += e;
#pragma unroll
        for (int j = 0; j < 8; j++)
            acc[j] += e * bf2f(hv[j]);
    }
    z += __shfl_xor(z, 32, 64);
#pragma unroll
    for (int j = 0; j < 8; j++)
        acc[j] += __shfl_xor(acc[j], 32, 64);

    if (lane < 32) {
        float inv = 1.f / (z + 1e-16f);
        float4 bv0 = *(const float4*)&bias[c0],   bv1 = *(const float4*)&bias[c0 + 4];
        float4 gv0 = *(const float4*)&gam[c0],    gv1 = *(const float4*)&gam[c0 + 4];
        float4 be0 = *(const float4*)&bet[c0],    be1 = *(const float4*)&bet[c0 + 4];
        float4 mv0 = *(const float4*)&bmean[c0],  mv1 = *(const float4*)&bmean[c0 + 4];
        float4 vv0 = *(const float4*)&bvar[c0],   vv1 = *(const float4*)&bvar[c0 + 4];
        float bs[8] = {bv0.x, bv0.y, bv0.z, bv0.w, bv1.x, bv1.y, bv1.z, bv1.w};
        float gs[8] = {gv0.x, gv0.y, gv0.z, gv0.w, gv1.x, gv1.y, gv1.z, gv1.w};
        float bes[8] = {be0.x, be0.y, be0.z, be0.w, be1.x, be1.y, be1.z, be1.w};
        float ms[8] = {mv0.x, mv0.y, mv0.z, mv0.w, mv1.x, mv1.y, mv1.z, mv1.w};
        float vs[8] = {vv0.x, vv0.y, vv0.z, vv0.w, vv1.x, vv1.y, vv1.z, vv1.w};
        float rs[8] = {};
        if (residb) {
            ushort8v rv = *(const ushort8v*)&residb[(unsigned)n * 256u + c0];
#pragma unroll
            for (int j = 0; j < 8; j++) rs[j] = bf2f(rv[j]);
        }
        ushort8v ob;
#pragma unroll
        for (int j = 0; j < 8; j++) {
            float val = acc[j] * inv + bs[j];
            val = (val - ms[j]) * rsqrtf(vs[j] + BN_EPS) * gs[j] + bes[j];
            val += rs[j];
            val = (val > 0.f) ? val : expm1f(val);   // ELU
            ob[j] = f2bf(val);
        }
        *(ushort8v*)&outb[(unsigned)n * 256u + c0] = ob;
    }
}

// ---------------- fused pooling + output heads ----------------
__global__ void poolhead_kernel(const ushort* __restrict__ hbf, const int* __restrict__ gstart,
                                const float* __restrict__ ow0, const float* __restrict__ ob0,
                                const float* __restrict__ ow1, const float* __restrict__ ob1,
                                float* __restrict__ out) {
    int g = blockIdx.x;
    int t = threadIdx.x;
    int s = gstart[g], e = gstart[g + 1];
    float sum = 0.f, mx = -INFINITY;
    for (int n = s; n < e; n++) {
        float v = bf2f(hbf[(unsigned)n * 256u + t]);
        sum += v;
        mx = fmaxf(mx, v);
    }
    int cnt = e - s;
    float mean = sum / fmaxf((float)cnt, 1.f);
    if (cnt == 0) mx = 0.f;

    float a0[3], a1[3];
#pragma unroll
    for (int j = 0; j < 3; j++) {
        a0[j] = mean * ow0[t * 3 + j] + sum * ow0[(256 + t) * 3 + j] + mx * ow0[(512 + t) * 3 + j];
        a1[j] = mean * ow1[t * 3 + j] + sum * ow1[(256 + t) * 3 + j] + mx * ow1[(512 + t) * 3 + j];
    }
    __shared__ float sd[6][256];
#pragma unroll
    for (int j = 0; j < 3; j++) { sd[j][t] = a0[j]; sd[3 + j][t] = a1[j]; }
    __syncthreads();
    for (int off = 128; off; off >>= 1) {
        if (t < off) {
#pragma unroll
            for (int j = 0; j < 6; j++) sd[j][t] += sd[j][t + off];
        }
        __syncthreads();
    }
    if (t < 3) {
        out[g * 3 + t] = sd[t][0] + ob0[t];
        out[1536 + g * 3 + t] = sd[3 + t][0] + ob1[t];
    }
}

// ---------------- launch ----------------
extern "C" void kernel_launch(void* const* d_in, const int* in_sizes, int n_in,
                              void* d_out, int out_size, void* d_ws, size_t ws_size,
                              hipStream_t stream) {
    const float* x     = (const float*)d_in[0];
    const int*   ei    = (const int*)d_in[1];
    const int*   batch = (const int*)d_in[2];
    const float* W[3]  = {(const float*)d_in[3], (const float*)d_in[11], (const float*)d_in[19]};
    const float* AS[3] = {(const float*)d_in[4], (const float*)d_in[12], (const float*)d_in[20]};
    const float* AD[3] = {(const float*)d_in[5], (const float*)d_in[13], (const float*)d_in[21]};
    const float* B[3]  = {(const float*)d_in[6], (const float*)d_in[14], (const float*)d_in[22]};
    const float* GM[3] = {(const float*)d_in[7], (const float*)d_in[15], (const float*)d_in[23]};
    const float* BE[3] = {(const float*)d_in[8], (const float*)d_in[16], (const float*)d_in[24]};
    const float* M[3]  = {(const float*)d_in[9], (const float*)d_in[17], (const float*)d_in[25]};
    const float* V[3]  = {(const float*)d_in[10], (const float*)d_in[18], (const float*)d_in[26]};
    const float* ow0 = (const float*)d_in[27];
    const float* ob0 = (const float*)d_in[28];
    const float* ow1 = (const float*)d_in[29];
    const float* ob1 = (const float*)d_in[30];
    float* out = (float*)d_out;

    // workspace carve
    char* p = (char*)d_ws;
    int* fill   = (int*)p;  p += (size_t)N_NODES * 4;
    int* rowptr = (int*)p;  p += (size_t)(N_NODES + 1) * 4;
    int* esrc   = (int*)p;  p += (size_t)EP * 4;
    int* gstart = (int*)p;  p += (size_t)(G_GRAPHS + 1) * 4;
    int* bsum   = (int*)p;  p += (size_t)(NB_SCAN + 1) * 4;
    p = (char*)(((uintptr_t)p + 255) & ~(uintptr_t)255);
    ushort* hb    = (ushort*)p; p += (size_t)N_NODES * HID * 2;      // GEMM out (bf16)
    ushort* curhb = (ushort*)p; p += (size_t)N_NODES * HID * 2;      // layer out (bf16)
    ushort* xb    = (ushort*)p; p += (size_t)N_NODES * 128 * 2;      // x bf16
    ushort* Wt0   = (ushort*)p; p += (size_t)256 * 128 * 2;
    ushort* Wt1   = (ushort*)p; p += (size_t)256 * 256 * 2;
    ushort* Wt2   = (ushort*)p; p += (size_t)256 * 256 * 2;
    float* ssrc   = (float*)p;  p += (size_t)N_NODES * HEADS * 4;
    float* sdst   = (float*)p;  p += (size_t)N_NODES * HEADS * 4;

    hipMemsetAsync(fill, 0, (size_t)N_NODES * 4, stream);

    prep_kernel<<<NB_PREP, 256, 0, stream>>>(x, xb, W[0], W[1], W[2], Wt0, Wt1, Wt2,
                                             ei, fill, batch, gstart);
    scan1_kernel<<<NB_SCAN, 1024, 0, stream>>>(fill, rowptr, bsum);
    scan3_kernel<<<NB_SCAN, 1024, 0, stream>>>(rowptr, fill, bsum);
    scatter_kernel<<<(EP + 255) / 256, 256, 0, stream>>>(ei, fill, esrc);

    const ushort* Wt[3] = {Wt0, Wt1, Wt2};
    dim3 ggrid((N_NODES + BM - 1) / BM, HID / BN);
    int sgrid = N_NODES / 8;            // 6250 blocks, 8 nodes per block
    int agrid = (N_NODES + 3) / 4;

    // layer 1 (input xb, K=128, no residual)
    gemm_kernel<<<ggrid, 256, 0, stream>>>(xb, Wt[0], hb, N_NODES, 128);
    score_kernel<<<sgrid, 256, 0, stream>>>(hb, AS[0], AD[0], ssrc, sdst);
    agg_kernel<<<agrid, 256, 0, stream>>>(hb, ssrc, sdst, rowptr, esrc,
                                          B[0], GM[0], BE[0], M[0], V[0],
                                          nullptr, curhb);
    // layers 2,3: residual read + output write both bf16, in place on curhb
    for (int l = 1; l < 3; l++) {
        gemm_kernel<<<ggrid, 256, 0, stream>>>(curhb, Wt[l], hb, N_NODES, 256);
        score_kernel<<<sgrid, 256, 0, stream>>>(hb, AS[l], AD[l], ssrc, sdst);
        agg_kernel<<<agrid, 256, 0, stream>>>(hb, ssrc, sdst, rowptr, esrc,
                                              B[l], GM[l], BE[l], M[l], V[l],
                                              curhb, curhb);
    }

    // fused pooling + heads
    poolhead_kernel<<<G_GRAPHS, 256, 0, stream>>>(curhb, gstart, ow0, ob0, ow1, ob1, out);
}